// Round 6
// baseline (380.477 us; speedup 1.0000x reference)
//
#include <hip/hip_runtime.h>
#include <hip/hip_cooperative_groups.h>
#include <stdint.h>

namespace cg = cooperative_groups;

#define NB   8
#define NC   256
#define NT   1024
#define NM   512
#define NNEG 100

typedef unsigned short u16;
typedef unsigned long long u64;
typedef __attribute__((ext_vector_type(8))) short bf16x8;
typedef __attribute__((ext_vector_type(4))) float f32x4;

// ---------------- Threefry-2x32-20 (JAX) ----------------
__device__ __forceinline__ unsigned rotl32(unsigned x, int d) {
  return (x << d) | (x >> (32 - d));
}

__device__ unsigned threefry_bits(unsigned i) {
  const unsigned half = 1048576u; // 2^20
  const bool lo = i < half;
  unsigned v0 = lo ? i : (i - half);
  unsigned v1 = lo ? (i + half) : i;
  const unsigned k0 = 0u, k1 = 42u;
  const unsigned k2 = k0 ^ k1 ^ 0x1BD11BDAu;
  v0 += k0; v1 += k1;
#define TF_R(r) { v0 += v1; v1 = rotl32(v1, r); v1 ^= v0; }
  TF_R(13) TF_R(15) TF_R(26) TF_R(6)
  v0 += k1; v1 += k2 + 1u;
  TF_R(17) TF_R(29) TF_R(16) TF_R(24)
  v0 += k2; v1 += k0 + 2u;
  TF_R(13) TF_R(15) TF_R(26) TF_R(6)
  v0 += k0; v1 += k1 + 3u;
  TF_R(17) TF_R(29) TF_R(16) TF_R(24)
  v0 += k1; v1 += k2 + 4u;
  TF_R(13) TF_R(15) TF_R(26) TF_R(6)
  v0 += k2; v1 += k0 + 5u;
#undef TF_R
  return lo ? v0 : v1;
}

// ============ single cooperative kernel: compact -> gemm -> loss -> reduce ===
__global__ __launch_bounds__(1024, 4) void mega(
    const float* __restrict__ feat, const void* __restrict__ maskp,
    const float* __restrict__ ctx,
    u16* __restrict__ MCh, u16* __restrict__ MCl,
    u16* __restrict__ MFh, u16* __restrict__ MFl,
    float* __restrict__ S, float* __restrict__ plp, float* __restrict__ pap,
    float* __restrict__ out) {
  cg::grid_group grid = cg::this_grid();
  __shared__ __align__(16) char sraw[61440];
  const int tid = threadIdx.x;
  const int beta = blockIdx.x;
  const int lane = tid & 63, wave = tid >> 6;

  //================= P1: compact + bf16 hi/lo split =================
  {
    float (*tle)[65] = (float (*)[65])sraw;         // 64*65*4 = 16640 B
    int* posl = (int*)(sraw + 16640);               // 64
    int* wsum = (int*)(sraw + 16640 + 256);         // 16
    int* det  = (int*)(sraw + 16640 + 256 + 64);    // 3
    const unsigned char* mb = (const unsigned char*)maskp;
    const int b = beta >> 5, mat = (beta >> 4) & 1, slab = beta & 15;
    const int t0 = slab * 64;

    if (tid < 3) det[tid] = 0;
    __syncthreads();
    { // mask storage-width detection (first 1024 elems; >=8KB in-bounds)
      int c1 = (mb[tid] != 0);
      int c4 = (((const unsigned*)mb)[tid] != 0u);
      int c8 = (((const u64*)mb)[tid] != 0ull);
#pragma unroll
      for (int off = 32; off; off >>= 1) {
        c1 += __shfl_xor(c1, off, 64);
        c4 += __shfl_xor(c4, off, 64);
        c8 += __shfl_xor(c8, off, 64);
      }
      if (lane == 0) { atomicAdd(&det[0], c1); atomicAdd(&det[1], c4); atomicAdd(&det[2], c8); }
    }
    __syncthreads();
    const int stride = (det[1] == 512) ? 4 : ((det[0] == 512) ? 1 : ((det[2] == 512) ? 8 : 4));

    // exclusive prefix of mask over row b (1 timestep per thread)
    size_t e = (size_t)b * NT + tid;
    int f;
    if (stride == 1)      f = (mb[e] != 0);
    else if (stride == 4) f = (((const unsigned*)mb)[e] != 0u);
    else                  f = (((const u64*)mb)[e] != 0ull);
    int incl = f;
#pragma unroll
    for (int off = 1; off < 64; off <<= 1) {
      int o = __shfl_up(incl, off, 64);
      if (lane >= off) incl += o;
    }
    if (lane == 63) wsum[wave] = incl;
    __syncthreads();
    int basep = 0;
#pragma unroll
    for (int w = 0; w < 16; ++w) if (w < wave) basep += wsum[w];
    int excl = basep + incl - f;
    if (tid >= t0 && tid < t0 + 64) posl[tid - t0] = f ? excl : -1;

    const float* src = (mat ? feat : ctx) + (size_t)b * NC * NT;
    u16* dh = (mat ? MFh : MCh) + (size_t)b * NM * NC;
    u16* dl = (mat ? MFl : MCl) + (size_t)b * NM * NC;
    const int grp = tid >> 6;
    for (int ch = 0; ch < 4; ++ch) {
      const int c0 = ch * 64;
      __syncthreads();
#pragma unroll
      for (int ci = 0; ci < 4; ++ci) {
        int cc = grp * 4 + ci;
        tle[cc][lane] = src[(size_t)(c0 + cc) * NT + t0 + lane];
      }
      __syncthreads();
#pragma unroll
      for (int tj = 0; tj < 4; ++tj) {
        int tt = grp * 4 + tj;
        int p = posl[tt];
        if (p >= 0) {
          float x = tle[lane][tt];
          unsigned xb = __float_as_uint(x);
          u16 hi = (u16)(xb >> 16);                      // truncate -> exact hi
          float rlo = x - __uint_as_float((unsigned)hi << 16);
          u16 lo = (u16)(__float_as_uint(rlo) >> 16);
          dh[(size_t)p * NC + c0 + lane] = hi;
          dl[(size_t)p * NC + c0 + lane] = lo;
        }
      }
    }
  }
  __threadfence();
  grid.sync();

  //================= P2: split-bf16 MFMA GEMM (128x64 tile, 16 waves) ========
  {
    u16* smem = (u16*)sraw;  // per buf: AH@0(128x40) AL@5120 BH@10240(64x40) BL@12800; stride 15360
    const int b = beta >> 5, mt = (beta >> 3) & 3, jt = beta & 7;
    const int m0 = mt * 128, j0 = jt * 64;
    const int wm = wave >> 2, wn = wave & 3;
    const int r = lane & 15, g = lane >> 4;

    const bool stA = (tid < 512), stB = (tid >= 512 && tid < 768);
    const int arow = tid & 127, ah2 = (tid >> 7) & 1, apl = (tid >> 8) & 1;
    const int q3 = tid & 255;
    const int brow = q3 & 63, bh2 = (q3 >> 6) & 1, bpl = (q3 >> 7) & 1;
    const u16* Asrc = (apl ? MCl : MCh) + (size_t)(b * NM + m0 + arow) * NC;
    const u16* Bsrc = (bpl ? MFl : MFh) + (size_t)(b * NM + j0 + brow) * NC;

    uint4 ra0, ra1, rb0, rb1;
    auto load_regs = [&](int c0) {
      if (stA) { const uint4* p = (const uint4*)(Asrc + c0 + 16 * ah2); ra0 = p[0]; ra1 = p[1]; }
      if (stB) { const uint4* p = (const uint4*)(Bsrc + c0 + 16 * bh2); rb0 = p[0]; rb1 = p[1]; }
    };
    auto write_lds = [&](int buf) {
      u16* base = smem + buf * 15360;
      if (stA) { u16* d = base + apl * 5120 + arow * 40 + 16 * ah2; *(uint4*)d = ra0; *(uint4*)(d + 8) = ra1; }
      if (stB) { u16* d = base + 10240 + bpl * 2560 + brow * 40 + 16 * bh2; *(uint4*)d = rb0; *(uint4*)(d + 8) = rb1; }
    };

    f32x4 z = {0.f, 0.f, 0.f, 0.f};
    f32x4 acc0 = z, acc1 = z;
    const int aro = (wm * 32 + r) * 40 + g * 8;
    const int bro = (wn * 16 + r) * 40 + g * 8;

    load_regs(0);
    write_lds(0);
    __syncthreads();

    for (int ks = 0; ks < 8; ++ks) {
      const int cur = ks & 1;
      if (ks < 7) load_regs((ks + 1) * 32);
      const u16* base = smem + cur * 15360;
      bf16x8 ah0 = *(const bf16x8*)(base + aro);
      bf16x8 ah1 = *(const bf16x8*)(base + aro + 640);
      bf16x8 al0 = *(const bf16x8*)(base + 5120 + aro);
      bf16x8 al1 = *(const bf16x8*)(base + 5120 + aro + 640);
      bf16x8 bh  = *(const bf16x8*)(base + 10240 + bro);
      bf16x8 bl  = *(const bf16x8*)(base + 12800 + bro);
      acc0 = __builtin_amdgcn_mfma_f32_16x16x32_bf16(ah0, bh, acc0, 0, 0, 0);
      acc0 = __builtin_amdgcn_mfma_f32_16x16x32_bf16(ah0, bl, acc0, 0, 0, 0);
      acc0 = __builtin_amdgcn_mfma_f32_16x16x32_bf16(al0, bh, acc0, 0, 0, 0);
      acc1 = __builtin_amdgcn_mfma_f32_16x16x32_bf16(ah1, bh, acc1, 0, 0, 0);
      acc1 = __builtin_amdgcn_mfma_f32_16x16x32_bf16(ah1, bl, acc1, 0, 0, 0);
      acc1 = __builtin_amdgcn_mfma_f32_16x16x32_bf16(al1, bh, acc1, 0, 0, 0);
      if (ks < 7) write_lds(cur ^ 1);
      __syncthreads();
    }

    float* Sb = S + (size_t)b * NM * NM;
#pragma unroll
    for (int m = 0; m < 2; ++m) {
      f32x4 a = m ? acc1 : acc0;
#pragma unroll
      for (int qq = 0; qq < 4; ++qq) {
        int rowi = m0 + wm * 32 + m * 16 + g * 4 + qq;
        int col  = j0 + wn * 16 + r;
        Sb[(size_t)rowi * NM + col] = a[qq];
      }
    }
  }
  __threadfence();
  grid.sync();

  //================= P3: top-100 selection + loss (2 rows per iter) ==========
  {
    unsigned* hist      = (unsigned*)sraw;                    // [2][256]
    u64* bkey           = (u64*)(sraw + 2048);                // [2][512]
    unsigned char* sfl  = (unsigned char*)(sraw + 10240);     // [2][512]
    int* scal           = (int*)(sraw + 11264);               // bcount[2],bbin[2],need[2]
    float* redM         = (float*)(sraw + 11264 + 32);        // [2][8]
    float* redE         = redM + 16;                          // [2][8]
    float* redA         = redE + 16;                          // [2][8]
    float* posn         = redA + 16;                          // [2]

    const int h = tid >> 9;          // half-block id (row slot)
    const int t = tid & 511;         // candidate index within row
    const int wq = t >> 6;           // wave-within-half: 0..7  (R5 bug: was &3)
    unsigned* H = hist + h * 256;
    u64* BK = bkey + h * 512;
    unsigned char* SF = sfl + h * 512;

    float sum_pl = 0.f, sum_pa = 0.f;

    for (int rr = 0; rr < 8; ++rr) {
      const int row = beta * 16 + rr * 2 + h;
      const int m = row & (NM - 1);
      const bool self = (t == m);

      __syncthreads();
      if (t < 256) H[t] = 0;
      if (t == 0) scal[h] = 0;
      SF[t] = 0;
      __syncthreads();

      unsigned bits = threefry_bits((unsigned)row * 512u + (unsigned)t);
      unsigned u = bits >> 9;
      unsigned key = (u << 9) | (unsigned)(511 - t);
      int bin = (int)(u >> 15);
      if (!self) atomicAdd(&H[bin], 1u);
      __syncthreads();

      if (t < 64) { // wave suffix scan over 256 bins (4 per lane)
        unsigned h0 = H[4 * t + 0], h1 = H[4 * t + 1];
        unsigned h2 = H[4 * t + 2], h3 = H[4 * t + 3];
        unsigned s = h0 + h1 + h2 + h3;
        unsigned suf = s;
#pragma unroll
        for (int off = 1; off < 64; off <<= 1) {
          unsigned o = __shfl_down(suf, off, 64);
          if (t + off < 64) suf += o;
        }
        unsigned a3 = suf - s;
        unsigned a2 = a3 + h3;
        unsigned a1 = a2 + h2;
        unsigned a0 = a1 + h1;
        if (a3 < NNEG && a3 + h3 >= NNEG) { scal[2 + h] = 4 * t + 3; scal[4 + h] = NNEG - (int)a3; }
        if (a2 < NNEG && a2 + h2 >= NNEG) { scal[2 + h] = 4 * t + 2; scal[4 + h] = NNEG - (int)a2; }
        if (a1 < NNEG && a1 + h1 >= NNEG) { scal[2 + h] = 4 * t + 1; scal[4 + h] = NNEG - (int)a1; }
        if (a0 < NNEG && a0 + h0 >= NNEG) { scal[2 + h] = 4 * t + 0; scal[4 + h] = NNEG - (int)a0; }
      }
      __syncthreads();

      const int bb = scal[2 + h];
      if (!self) {
        if (bin > bb) SF[t] = 1;
        else if (bin == bb) {
          int p = atomicAdd(&scal[h], 1);
          BK[p] = (((u64)key) << 1) | 1ull;
        }
      }
      __syncthreads();

      if (t == 0) { // resolve boundary bin (expected ~2 entries)
        int cnt = scal[h], need = scal[4 + h];
        for (int it = 0; it < need; ++it) {
          u64 best = 0ull; int bi = 0;
          for (int q = 0; q < cnt; ++q)
            if (BK[q] > best) { best = BK[q]; bi = q; }
          BK[bi] = 0ull;
          int tt = 511 - (int)((best >> 1) & 511ull);
          SF[tt] = 1;
        }
      }
      __syncthreads();

      const float* Srow = S + (size_t)row * NM;
      const bool act = (SF[t] != 0) || self;
      const float lv = Srow[t];

      float mv = act ? lv : -3.4e38f;
#pragma unroll
      for (int off = 32; off > 0; off >>= 1) mv = fmaxf(mv, __shfl_xor(mv, off, 64));
      if (lane == 0) redM[h * 8 + wq] = mv;
      __syncthreads();
      float mx = redM[h * 8 + 0];
#pragma unroll
      for (int q = 1; q < 8; ++q) mx = fmaxf(mx, redM[h * 8 + q]);

      float ev = 0.f, av = 0.f;
      if (act) {
        ev = __expf(lv - mx);
        float th = 1.f - 2.f / (__expf(2.f * lv) + 1.f);
        av = th * th;
      }
      if (self) posn[h] = ev;

      float es = ev, as = av;
#pragma unroll
      for (int off = 32; off > 0; off >>= 1) {
        es += __shfl_xor(es, off, 64);
        as += __shfl_xor(as, off, 64);
      }
      if (lane == 0) { redE[h * 8 + wq] = es; redA[h * 8 + wq] = as; }
      __syncthreads();

      if (t == 0) {
        float den = 0.f, aux = 0.f;
#pragma unroll
        for (int q = 0; q < 8; ++q) { den += redE[h * 8 + q]; aux += redA[h * 8 + q]; }
        sum_pl += posn[h] / den;
        sum_pa += aux;
      }
    }
    if (t == 0) { plp[beta * 2 + h] = sum_pl; pap[beta * 2 + h] = sum_pa; }
  }
  __threadfence();
  grid.sync();

  //================= P4: deterministic final reduction (block 0) =============
  if (beta == 0) {
    float* s1 = (float*)sraw;        // 512
    float* s2 = s1 + 512;
    if (tid < 512) { s1[tid] = plp[tid]; s2[tid] = pap[tid]; }
    __syncthreads();
    for (int off = 256; off > 0; off >>= 1) {
      if (tid < off) { s1[tid] += s1[tid + off]; s2[tid] += s2[tid + off]; }
      __syncthreads();
    }
    if (tid == 0) { out[0] = s1[0]; out[1] = s2[0]; }
  }
}

extern "C" void kernel_launch(void* const* d_in, const int* in_sizes, int n_in,
                              void* d_out, int out_size, void* d_ws, size_t ws_size,
                              hipStream_t stream) {
  const float* feat = (const float*)d_in[0];  // feat_proj [B,C,T]
  const void*  mask = d_in[1];                // mask [B,T] bool
  const float* ctx  = (const float*)d_in[2];  // context_output [B,C,T]
  float* out = (float*)d_out;

  char* ws = (char*)d_ws;
  u16*   MCh = (u16*)ws;                           // 2 MB [B,M,C] bf16 hi (ctx)
  u16*   MCl = (u16*)(ws + (2u << 20));            // 2 MB lo
  u16*   MFh = (u16*)(ws + (4u << 20));            // 2 MB (feat)
  u16*   MFl = (u16*)(ws + (6u << 20));            // 2 MB
  float* S   = (float*)(ws + (8u << 20));          // 8 MB [B,M,M] f32
  float* plp = (float*)(ws + (16u << 20));         // 512 floats
  float* pap = plp + 512;                          // 512 floats

  void* args[] = { (void*)&feat, (void*)&mask, (void*)&ctx,
                   (void*)&MCh, (void*)&MCl, (void*)&MFh, (void*)&MFl,
                   (void*)&S, (void*)&plp, (void*)&pap, (void*)&out };
  hipLaunchCooperativeKernel((void*)mega, dim3(256), dim3(1024), args, 0, stream);
}

// Round 8
// 52.501 us; speedup vs baseline: 7.2471x; 7.2471x over previous
//
#include <hip/hip_runtime.h>
#include <stdint.h>

#define NB   8
#define NC   256
#define NT   1024
#define NM   512
#define NNEG 100

typedef unsigned short u16;
typedef unsigned long long u64;
typedef __attribute__((ext_vector_type(8))) short bf16x8;
typedef __attribute__((ext_vector_type(4))) float f32x4;

// wave-level LDS visibility fence: drain this wave's LDS ops so other lanes'
// writes are readable (wave-synchronous programming without __syncthreads).
#define WAVE_LDS_FENCE() asm volatile("s_waitcnt lgkmcnt(0)" ::: "memory")

// ---------------- Threefry-2x32-20 (JAX) ----------------
__device__ __forceinline__ unsigned rotl32(unsigned x, int d) {
  return (x << d) | (x >> (32 - d));
}

__device__ unsigned threefry_bits(unsigned i) {
  const unsigned half = 1048576u; // 2^20
  const bool lo = i < half;
  unsigned v0 = lo ? i : (i - half);
  unsigned v1 = lo ? (i + half) : i;
  const unsigned k0 = 0u, k1 = 42u;
  const unsigned k2 = k0 ^ k1 ^ 0x1BD11BDAu;
  v0 += k0; v1 += k1;
#define TF_R(r) { v0 += v1; v1 = rotl32(v1, r); v1 ^= v0; }
  TF_R(13) TF_R(15) TF_R(26) TF_R(6)
  v0 += k1; v1 += k2 + 1u;
  TF_R(17) TF_R(29) TF_R(16) TF_R(24)
  v0 += k2; v1 += k0 + 2u;
  TF_R(13) TF_R(15) TF_R(26) TF_R(6)
  v0 += k0; v1 += k1 + 3u;
  TF_R(17) TF_R(29) TF_R(16) TF_R(24)
  v0 += k1; v1 += k2 + 4u;
  TF_R(13) TF_R(15) TF_R(26) TF_R(6)
  v0 += k2; v1 += k0 + 5u;
#undef TF_R
  return lo ? v0 : v1;
}

// ---------------- Kernel 1: compact + bf16 hi/lo split (R4, validated) ------
__global__ __launch_bounds__(256) void k_compact(const float* __restrict__ ctx,
                                                 const float* __restrict__ feat,
                                                 const void* __restrict__ maskp,
                                                 u16* __restrict__ MCh, u16* __restrict__ MCl,
                                                 u16* __restrict__ MFh, u16* __restrict__ MFl) {
  __shared__ float lds[64][129];
  __shared__ int posl[128];
  __shared__ int wsum[4];
  __shared__ int det[3];
  const int tid = threadIdx.x;
  const int lane = tid & 63, wid = tid >> 6;
  const int t0 = blockIdx.x * 128;
  const int b = blockIdx.y >> 1, mat = blockIdx.y & 1;
  const unsigned char* mb = (const unsigned char*)maskp;

  if (tid < 3) det[tid] = 0;
  __syncthreads();
  {
    int c1 = 0, c4 = 0, c8 = 0;
    for (int j = tid; j < 1024; j += 256) {
      c1 += (mb[j] != 0);
      c4 += (((const unsigned*)mb)[j] != 0u);
      c8 += (((const u64*)mb)[j] != 0ull);
    }
#pragma unroll
    for (int off = 32; off; off >>= 1) {
      c1 += __shfl_xor(c1, off, 64);
      c4 += __shfl_xor(c4, off, 64);
      c8 += __shfl_xor(c8, off, 64);
    }
    if (lane == 0) { atomicAdd(&det[0], c1); atomicAdd(&det[1], c4); atomicAdd(&det[2], c8); }
  }
  __syncthreads();
  const int stride = (det[1] == 512) ? 4 : ((det[0] == 512) ? 1 : ((det[2] == 512) ? 8 : 4));

  int f4[4]; int s = 0;
#pragma unroll
  for (int j = 0; j < 4; ++j) {
    int tt = 4 * tid + j;
    size_t e = (size_t)b * NT + tt;
    int f;
    if (stride == 1)      f = (mb[e] != 0);
    else if (stride == 4) f = (((const unsigned*)mb)[e] != 0u);
    else                  f = (((const u64*)mb)[e] != 0ull);
    f4[j] = f; s += f;
  }
  int incl = s;
#pragma unroll
  for (int off = 1; off < 64; off <<= 1) {
    int o = __shfl_up(incl, off, 64);
    if (lane >= off) incl += o;
  }
  if (lane == 63) wsum[wid] = incl;
  __syncthreads();
  int wbase = 0;
#pragma unroll
  for (int w = 0; w < 4; ++w) if (w < wid) wbase += wsum[w];
  int excl = wbase + incl - s;
#pragma unroll
  for (int j = 0; j < 4; ++j) {
    int tt = 4 * tid + j;
    if (tt >= t0 && tt < t0 + 128) posl[tt - t0] = f4[j] ? excl : -1;
    excl += f4[j];
  }

  const float* src = (mat ? feat : ctx) + (size_t)b * NC * NT;
  u16* dh = (mat ? MFh : MCh) + (size_t)b * NM * NC;
  u16* dl = (mat ? MFl : MCl) + (size_t)b * NM * NC;

  const int c4i = tid >> 6, tl = tid & 63, tr = tid >> 6;
  for (int chunk = 0; chunk < 4; ++chunk) {
    int c0 = chunk * 64;
    __syncthreads();
    for (int ci = 0; ci < 16; ++ci) {
      int cc = c4i * 16 + ci;
#pragma unroll
      for (int tj = 0; tj < 2; ++tj) {
        int tt = tl + 64 * tj;
        lds[cc][tt] = src[(size_t)(c0 + cc) * NT + t0 + tt];
      }
    }
    __syncthreads();
    for (int tt = tr; tt < 128; tt += 4) {
      int p = posl[tt];
      if (p >= 0) {
        float x = lds[tl][tt];
        unsigned xb = __float_as_uint(x);
        u16 hi = (u16)(xb >> 16);
        float rlo = x - __uint_as_float((unsigned)hi << 16);
        u16 lo = (u16)(__float_as_uint(rlo) >> 16);
        dh[(size_t)p * NC + c0 + tl] = hi;
        dl[(size_t)p * NC + c0 + tl] = lo;
      }
    }
  }
}

// ---------------- Kernel 2: split-bf16 MFMA GEMM, 64x64 tile, 512 blocks ----
__global__ __launch_bounds__(256) void k_gemm(const u16* __restrict__ MCh, const u16* __restrict__ MCl,
                                              const u16* __restrict__ MFh, const u16* __restrict__ MFl,
                                              float* __restrict__ S) {
  __shared__ u16 smem[2][10240]; // per buf: A(plane*64+row)[128][40] @0, B @5120
  const int tid = threadIdx.x;
  const int b = blockIdx.z, m0 = blockIdx.y * 64, j0 = blockIdx.x * 64;
  const int wave = tid >> 6, lane = tid & 63;
  const int wm = wave >> 1, wn = wave & 1;
  const int r = lane & 15, g = lane >> 4;

  const int srow = tid >> 1;           // 0..127 = plane*64 + mrow
  const int splane = srow >> 6;
  const int smrow = srow & 63;
  const int shalf = tid & 1;
  const u16* Asrc = (splane ? MCl : MCh) + (size_t)(b * NM + m0 + smrow) * NC + shalf * 16;
  const u16* Bsrc = (splane ? MFl : MFh) + (size_t)(b * NM + j0 + smrow) * NC + shalf * 16;
  const int sdst = srow * 40 + shalf * 16;

  uint4 ra0, ra1, rb0, rb1;
  auto load_regs = [&](int c0) {
    const uint4* p = (const uint4*)(Asrc + c0); ra0 = p[0]; ra1 = p[1];
    const uint4* q = (const uint4*)(Bsrc + c0); rb0 = q[0]; rb1 = q[1];
  };
  auto write_lds = [&](int buf) {
    u16* d = smem[buf] + sdst;
    *(uint4*)d = ra0; *(uint4*)(d + 8) = ra1;
    u16* e = smem[buf] + 5120 + sdst;
    *(uint4*)e = rb0; *(uint4*)(e + 8) = rb1;
  };

  f32x4 zero = {0.f, 0.f, 0.f, 0.f};
  f32x4 acc[2][2];
#pragma unroll
  for (int m = 0; m < 2; ++m)
#pragma unroll
    for (int n = 0; n < 2; ++n) acc[m][n] = zero;

  load_regs(0);
  write_lds(0);
  __syncthreads();

  for (int ks = 0; ks < 8; ++ks) {
    const int cur = ks & 1;
    if (ks < 7) load_regs((ks + 1) * 32);
    const u16* base = smem[cur];
    bf16x8 ah[2], al[2], bh[2], bl[2];
#pragma unroll
    for (int m = 0; m < 2; ++m) {
      ah[m] = *(const bf16x8*)(base + (wm * 32 + m * 16 + r) * 40 + g * 8);
      al[m] = *(const bf16x8*)(base + (64 + wm * 32 + m * 16 + r) * 40 + g * 8);
    }
#pragma unroll
    for (int n = 0; n < 2; ++n) {
      bh[n] = *(const bf16x8*)(base + 5120 + (wn * 32 + n * 16 + r) * 40 + g * 8);
      bl[n] = *(const bf16x8*)(base + 5120 + (64 + wn * 32 + n * 16 + r) * 40 + g * 8);
    }
#pragma unroll
    for (int m = 0; m < 2; ++m)
#pragma unroll
      for (int n = 0; n < 2; ++n) {
        acc[m][n] = __builtin_amdgcn_mfma_f32_16x16x32_bf16(ah[m], bh[n], acc[m][n], 0, 0, 0);
        acc[m][n] = __builtin_amdgcn_mfma_f32_16x16x32_bf16(ah[m], bl[n], acc[m][n], 0, 0, 0);
        acc[m][n] = __builtin_amdgcn_mfma_f32_16x16x32_bf16(al[m], bh[n], acc[m][n], 0, 0, 0);
      }
    if (ks < 7) write_lds(cur ^ 1);
    __syncthreads();
  }

  float* Sb = S + (size_t)b * NM * NM;
#pragma unroll
  for (int m = 0; m < 2; ++m)
#pragma unroll
    for (int n = 0; n < 2; ++n)
#pragma unroll
      for (int q = 0; q < 4; ++q) {
        int rowi = m0 + wm * 32 + m * 16 + g * 4 + q;
        int col  = j0 + wn * 32 + n * 16 + r;
        Sb[(size_t)rowi * NM + col] = acc[m][n][q];
      }
}

// ---------------- Kernel 3: wave-per-row top-100 + loss (fenced) ------------
// 8 waves/block, one row each. Cross-lane LDS handoffs within a wave REQUIRE
// an lgkmcnt drain (no __syncthreads here): atomics/stores are still in
// flight when the next instruction issues (R7 bug: stale hist -> threshold
// bin too low -> over-selection inflating aux by ~172k).
__global__ __launch_bounds__(512) void k_loss(const float* __restrict__ S,
                                              float* __restrict__ pl,
                                              float* __restrict__ pa) {
  __shared__ unsigned hist[8][256];
  __shared__ u64 bk[8][32];
  __shared__ int bcnt[8], bbin[8], bneed[8];
  __shared__ unsigned char sf[8][512];

  const int tid = threadIdx.x;
  const int lane = tid & 63, wv = tid >> 6;
  const int row = blockIdx.x * 8 + wv;
  const int m = row & (NM - 1);

#pragma unroll
  for (int q = 0; q < 4; ++q) hist[wv][lane * 4 + q] = 0;
#pragma unroll
  for (int j = 0; j < 8; ++j) sf[wv][j * 64 + lane] = 0;
  if (lane == 0) bcnt[wv] = 0;

  unsigned keys[8]; int bins[8]; bool selfj[8];
#pragma unroll
  for (int j = 0; j < 8; ++j) {
    int t = j * 64 + lane;
    unsigned bits = threefry_bits((unsigned)row * 512u + (unsigned)t);
    unsigned u = bits >> 9;
    keys[j] = (u << 9) | (unsigned)(511 - t);
    bins[j] = (int)(u >> 15);
    selfj[j] = (t == m);
    if (!selfj[j]) atomicAdd(&hist[wv][bins[j]], 1u);
  }
  WAVE_LDS_FENCE();  // F1: hist atomics visible to scan reads

  { // suffix scan over 256 bins, 4 per lane (wave-synchronous)
    unsigned h0 = hist[wv][4 * lane + 0], h1 = hist[wv][4 * lane + 1];
    unsigned h2 = hist[wv][4 * lane + 2], h3 = hist[wv][4 * lane + 3];
    unsigned s = h0 + h1 + h2 + h3;
    unsigned suf = s;
#pragma unroll
    for (int off = 1; off < 64; off <<= 1) {
      unsigned o = __shfl_down(suf, off, 64);
      if (lane + off < 64) suf += o;
    }
    unsigned a3 = suf - s;
    unsigned a2 = a3 + h3;
    unsigned a1 = a2 + h2;
    unsigned a0 = a1 + h1;
    if (a3 < NNEG && a3 + h3 >= NNEG) { bbin[wv] = 4 * lane + 3; bneed[wv] = NNEG - (int)a3; }
    if (a2 < NNEG && a2 + h2 >= NNEG) { bbin[wv] = 4 * lane + 2; bneed[wv] = NNEG - (int)a2; }
    if (a1 < NNEG && a1 + h1 >= NNEG) { bbin[wv] = 4 * lane + 1; bneed[wv] = NNEG - (int)a1; }
    if (a0 < NNEG && a0 + h0 >= NNEG) { bbin[wv] = 4 * lane + 0; bneed[wv] = NNEG - (int)a0; }
  }
  WAVE_LDS_FENCE();  // F2: bbin/bneed stores visible to all lanes

  const int bb = bbin[wv];
#pragma unroll
  for (int j = 0; j < 8; ++j) {
    if (!selfj[j] && bins[j] == bb) {
      int p = atomicAdd(&bcnt[wv], 1);
      bk[wv][p & 31] = (((u64)keys[j]) << 1) | 1ull;
    }
  }
  WAVE_LDS_FENCE();  // F3: bk/bcnt visible to lane 0

  if (lane == 0) { // resolve boundary bin (expected ~2 entries)
    int cnt = bcnt[wv]; if (cnt > 32) cnt = 32;
    int need = bneed[wv];
    for (int it = 0; it < need; ++it) {
      u64 best = 0ull; int bi = 0;
      for (int q = 0; q < cnt; ++q)
        if (bk[wv][q] > best) { best = bk[wv][q]; bi = q; }
      bk[wv][bi] = 0ull;
      int tt = 511 - (int)((best >> 1) & 511ull);
      sf[wv][tt] = 1;
    }
  }
  WAVE_LDS_FENCE();  // F4: lane 0's sf stores visible to all lanes

  // softmax + tanh^2, fully in-wave
  const float* Srow = S + (size_t)row * NM;
  float lv[8]; bool act[8];
  float mv = -3.4e38f;
#pragma unroll
  for (int j = 0; j < 8; ++j) {
    lv[j] = Srow[j * 64 + lane];
    act[j] = selfj[j] || (bins[j] > bb && !selfj[j]) || (sf[wv][j * 64 + lane] != 0);
    if (act[j]) mv = fmaxf(mv, lv[j]);
  }
#pragma unroll
  for (int off = 32; off > 0; off >>= 1) mv = fmaxf(mv, __shfl_xor(mv, off, 64));

  float es = 0.f, as = 0.f, ps = 0.f;
#pragma unroll
  for (int j = 0; j < 8; ++j) {
    if (act[j]) {
      float e = __expf(lv[j] - mv);
      float th = 1.f - 2.f / (__expf(2.f * lv[j]) + 1.f);
      es += e; as += th * th;
      if (selfj[j]) ps = e;
    }
  }
#pragma unroll
  for (int off = 32; off > 0; off >>= 1) {
    es += __shfl_xor(es, off, 64);
    as += __shfl_xor(as, off, 64);
    ps += __shfl_xor(ps, off, 64);
  }
  if (lane == 0) { pl[row] = ps / es; pa[row] = as; }
}

// ---------------- Kernel 4: deterministic final reduction ----------------
__global__ __launch_bounds__(1024) void k_red(const float* __restrict__ pl,
                                              const float* __restrict__ pa,
                                              float* __restrict__ out) {
  __shared__ float s1[1024], s2[1024];
  const int t = threadIdx.x;
  float a = 0.f, b = 0.f;
  for (int q = t; q < NB * NM; q += 1024) { a += pl[q]; b += pa[q]; }
  s1[t] = a; s2[t] = b;
  __syncthreads();
  for (int off = 512; off > 0; off >>= 1) {
    if (t < off) { s1[t] += s1[t + off]; s2[t] += s2[t + off]; }
    __syncthreads();
  }
  if (t == 0) { out[0] = s1[0]; out[1] = s2[0]; }
}

extern "C" void kernel_launch(void* const* d_in, const int* in_sizes, int n_in,
                              void* d_out, int out_size, void* d_ws, size_t ws_size,
                              hipStream_t stream) {
  const float* feat = (const float*)d_in[0];  // feat_proj [B,C,T]
  const void*  mask = d_in[1];                // mask [B,T] bool
  const float* ctx  = (const float*)d_in[2];  // context_output [B,C,T]
  float* out = (float*)d_out;

  char* ws = (char*)d_ws;
  u16*   MCh = (u16*)ws;                           // 2 MB [B,M,C] bf16 hi (ctx)
  u16*   MCl = (u16*)(ws + (2u << 20));            // 2 MB lo
  u16*   MFh = (u16*)(ws + (4u << 20));            // 2 MB (feat)
  u16*   MFl = (u16*)(ws + (6u << 20));            // 2 MB
  float* S   = (float*)(ws + (8u << 20));          // 8 MB [B,M,M] f32
  float* pl  = (float*)(ws + (16u << 20));         // 16 KB
  float* pa  = pl + NB * NM;                       // 16 KB

  dim3 gc(NT / 128, NB * 2);
  k_compact<<<gc, 256, 0, stream>>>(ctx, feat, mask, MCh, MCl, MFh, MFl);

  dim3 g2(NM / 64, NM / 64, NB);  // 8 x 8 x 8 = 512 blocks
  k_gemm<<<g2, 256, 0, stream>>>(MCh, MCl, MFh, MFl, S);

  k_loss<<<NB * NM / 8, 512, 0, stream>>>(S, pl, pa);

  k_red<<<1, 1024, 0, stream>>>(pl, pa, out);
}